// Round 7
// baseline (33.410 us; speedup 1.0000x reference)
//
#include <hip/hip_runtime.h>
#include <hip/hip_bf16.h>
#include <cstdint>
#include <cstddef>

using short8  = __attribute__((ext_vector_type(8))) short;
using short4v = __attribute__((ext_vector_type(4))) short;
using f32x4   = __attribute__((ext_vector_type(4))) float;

constexpr int NB = 16, NC = 512, ND = 256, NK = 32;
constexpr int ROWS = 32;               // rows per block (two 16-row M frags)
constexpr int NROW = NB * NC;          // 8192
constexpr int NBLK = NROW / ROWS;      // 256
constexpr int NTHR = 1024;             // 16 waves
constexpr int LDP  = ND + 8;           // ushort row stride (528 B)
constexpr int PLD  = 516;              // P f32 row stride

// LDS union layout (bytes): [P f32 32x516 | union s_ab 32x528 bf16][s_w][s_hb]
constexpr int LDS_W   = ROWS * PLD * 4;              // 66048
constexpr int LDS_HB  = LDS_W + ROWS * LDP * 2;      // +33792
constexpr int LDS_TOT = LDS_HB + ROWS * LDP * 2;     // 133632 -> 1 block/CU, 16 waves

// d_ws layout (bf16 element offsets):
//  vW frags [0,65536) ; oW [65536,131072) ; gW [131072,262144)
//  h  frags [262144 + b*131072): frag fs=ks*16+nt,
//     elem = PHB + b*131072 + ((ks*16+nt)*64 + lane)*8 + j
//          == h[b][ks*32+(lane>>4)*8+j][nt*16+(lane&15)]
constexpr int PVW = 0;
constexpr int POW = 65536;
constexpr int PGW = 131072;
constexpr int PHB = 262144;
constexpr size_t WS_NEED = (size_t)(PHB + NB * 131072) * 2;   // ~4.7 MB

static __device__ __forceinline__ unsigned short f2bf(float f) {
    __hip_bfloat16 b = __float2bfloat16(f);
    return *reinterpret_cast<unsigned short*>(&b);
}
static __device__ __forceinline__ short4v f2bf4(float4 v) {
    short4v r;
    r[0] = (short)f2bf(v.x); r[1] = (short)f2bf(v.y);
    r[2] = (short)f2bf(v.z); r[3] = (short)f2bf(v.w);
    return r;
}

// ---------------------------------------------------------------------------
// merged pack: blocks 0..127 pack vW/oW/gW; blocks 128..1151 pack h
// ---------------------------------------------------------------------------
__global__ __launch_bounds__(256)
void stk_pack_all(const float* __restrict__ vW, const float* __restrict__ oW,
                  const float* __restrict__ gW, const float* __restrict__ h,
                  unsigned short* __restrict__ ws)
{
    const int blk = blockIdx.x;
    if (blk < 128) {
        const int tid  = blk * 256 + threadIdx.x;      // 32768 threads
        const int lane = tid & 63;
        const int fl   = tid >> 6;                     // fragment id 0..511
        const float* src; int nt, ks;
        if (fl < 128)      { src = vW; nt = fl >> 3;         ks = fl & 7;          }
        else if (fl < 256) { src = oW; nt = (fl - 128) >> 3; ks = (fl - 128) & 7;  }
        else               { src = gW; nt = (fl - 256) >> 4; ks = (fl - 256) & 15; }
        const int col = nt * 16 + (lane & 15);
        const int k0  = ks * 32 + (lane >> 4) * 8;
        short8 v;
        #pragma unroll
        for (int j = 0; j < 8; ++j)
            v[j] = (short)f2bf(src[(size_t)(k0 + j) * ND + col]);
        *reinterpret_cast<short8*>(&ws[(size_t)tid * 8]) = v;
    } else {
        const int tid  = (blk - 128) * 256 + threadIdx.x;   // 262144 threads
        const int lane = tid & 63;
        const int fs   = tid >> 6;                     // b*256 + ks*16 + nt
        const int b    = fs >> 8;
        const int ks   = (fs >> 4) & 15;
        const int nt   = fs & 15;
        const float* src = h + (size_t)b * NC * ND;
        const int col = nt * 16 + (lane & 15);
        const int k0  = ks * 32 + (lane >> 4) * 8;
        short8 v;
        #pragma unroll
        for (int j = 0; j < 8; ++j)
            v[j] = (short)f2bf(src[(size_t)(k0 + j) * ND + col]);
        *reinterpret_cast<short8*>(&ws[(size_t)PHB + (size_t)tid * 8]) = v;
    }
}

// ---------------------------------------------------------------------------
// main fused kernel: 32 rows/block, 1024 threads (16 waves), dense-P MFMA
// ---------------------------------------------------------------------------
__global__ __launch_bounds__(1024, 1)
void stk_mfma(const float* __restrict__ h,
              const int*   __restrict__ topk_idx,
              const float* __restrict__ topk_scores,
              const float* __restrict__ vb, const float* __restrict__ ob,
              const float* __restrict__ gb,
              const unsigned short* __restrict__ wsb,
              float* __restrict__ out)
{
    __shared__ __align__(16) char smem[LDS_TOT];
    float          (*s_P )[PLD] = reinterpret_cast<float(*)[PLD]>(smem);
    unsigned short (*s_ab)[LDP] = reinterpret_cast<unsigned short(*)[LDP]>(smem); // union w/ P
    unsigned short (*s_w )[LDP] = reinterpret_cast<unsigned short(*)[LDP]>(smem + LDS_W);
    unsigned short (*s_hb)[LDP] = reinterpret_cast<unsigned short(*)[LDP]>(smem + LDS_HB);

    const int t   = threadIdx.x;
    // XCD-aware bijective swizzle: 256 blocks, 8 XCDs -> 32 consecutive tiles
    // (= 2 batches) per XCD; h-slabs + weights stay L2-resident per XCD.
    const int bid = (int)blockIdx.x;
    const int swz = ((bid & 7) << 5) + (bid >> 3);
    const int m0  = swz * ROWS;
    const int batch = m0 >> 9;                        // C=512 rows per batch

    // ---- zero P (flat float4: 32*516/4 = 4128 vectors) ---------------------
    {
        float4* p4 = reinterpret_cast<float4*>(&s_P[0][0]);
        #pragma unroll
        for (int i = 0; i < 5; ++i) {
            const int j = t + i * NTHR;
            if (j < (ROWS * PLD) / 4) p4[j] = float4{0.f, 0.f, 0.f, 0.f};
        }
    }

    // ---- stage-h loads issued early (consumed after softmax) ---------------
    const int sr  = t >> 5;           // row 0..31
    const int sc8 = (t & 31) * 8;     // col chunk
    const float4 h0 = *reinterpret_cast<const float4*>(&h[(size_t)(m0 + sr) * ND + sc8]);
    const float4 h1 = *reinterpret_cast<const float4*>(&h[(size_t)(m0 + sr) * ND + sc8 + 4]);

    // ---- softmax over K (width-32 butterflies; one (r,k) per thread) -------
    const int k = t & 31;
    const int r = t >> 5;             // 0..31
    float att; int id;
    {
        const size_t off = (size_t)(m0 + r) * NK + k;
        const float s = topk_scores[off];
        id = topk_idx[off];
        float m = s;
        #pragma unroll
        for (int msk = 16; msk >= 1; msk >>= 1)
            m = fmaxf(m, __shfl_xor(m, msk));
        const float p = __expf(s - m);
        float Z = p;
        #pragma unroll
        for (int msk = 16; msk >= 1; msk >>= 1)
            Z += __shfl_xor(Z, msk);
        att = p / Z;
    }
    __syncthreads();                  // P zeroed everywhere

    // ---- scatter-add into dense P (ds_add handles duplicate idx) -----------
    atomicAdd(&s_P[r][id], att);

    // ---- store staged h as bf16 --------------------------------------------
    *reinterpret_cast<short4v*>(&s_hb[sr][sc8])     = f2bf4(h0);
    *reinterpret_cast<short4v*>(&s_hb[sr][sc8 + 4]) = f2bf4(h1);
    __syncthreads();                  // P complete + s_hb complete

    const int lane = t & 63;
    const int w    = t >> 6;          // wave 0..15
    const int nt   = w;               // this wave's N tile
    const int lr   = lane & 15;
    const int lg   = lane >> 4;

    // ---- GEMM1: wsum = P @ h_batch (16 k-slices, 2 M frags) ----------------
    {
        f32x4 acc[2] = {f32x4{0,0,0,0}, f32x4{0,0,0,0}};
        const unsigned short* hf = wsb + (size_t)PHB + (size_t)batch * 131072;
        #pragma unroll
        for (int ks = 0; ks < 16; ++ks) {
            const int kb = ks * 32 + lg * 8;
            const short8 b = *reinterpret_cast<const short8*>(
                &hf[(size_t)(((ks * 16 + nt) * 64 + lane) * 8)]);
            #pragma unroll
            for (int m = 0; m < 2; ++m) {
                const float4 a0 = *reinterpret_cast<const float4*>(&s_P[m * 16 + lr][kb]);
                const float4 a1 = *reinterpret_cast<const float4*>(&s_P[m * 16 + lr][kb + 4]);
                short8 a;
                a[0] = (short)f2bf(a0.x); a[1] = (short)f2bf(a0.y);
                a[2] = (short)f2bf(a0.z); a[3] = (short)f2bf(a0.w);
                a[4] = (short)f2bf(a1.x); a[5] = (short)f2bf(a1.y);
                a[6] = (short)f2bf(a1.z); a[7] = (short)f2bf(a1.w);
                acc[m] = __builtin_amdgcn_mfma_f32_16x16x32_bf16(a, b, acc[m], 0, 0, 0);
            }
        }
        #pragma unroll
        for (int m = 0; m < 2; ++m) {
            const int col = nt * 16 + lr;
            #pragma unroll
            for (int q = 0; q < 4; ++q)
                s_w[m * 16 + 4 * lg + q][col] = f2bf(acc[m][q]);
        }
    }
    __syncthreads();                  // s_w ready; s_P reads done

    // ---- GEMM2: agg = wsum @ vW + vb ---------------------------------------
    {
        const float bv = vb[nt * 16 + lr];
        f32x4 acc[2] = {f32x4{bv, bv, bv, bv}, f32x4{bv, bv, bv, bv}};
        #pragma unroll
        for (int ks = 0; ks < 8; ++ks) {
            const int kb = ks * 32 + lg * 8;
            const short8 b = *reinterpret_cast<const short8*>(
                &wsb[(size_t)(PVW + ((nt * 8 + ks) * 64 + lane) * 8)]);
            #pragma unroll
            for (int m = 0; m < 2; ++m) {
                const short8 a = *reinterpret_cast<const short8*>(&s_w[m * 16 + lr][kb]);
                acc[m] = __builtin_amdgcn_mfma_f32_16x16x32_bf16(a, b, acc[m], 0, 0, 0);
            }
        }
        #pragma unroll
        for (int m = 0; m < 2; ++m) {
            const int col = nt * 16 + lr;
            #pragma unroll
            for (int q = 0; q < 4; ++q)
                s_ab[m * 16 + 4 * lg + q][col] = f2bf(acc[m][q]);
        }
    }
    __syncthreads();

    // ---- GEMM3: o = agg@oW + ob ; g = h@gW_h + agg@gW_a + gb ; epilogue ----
    {
        const float bo = ob[nt * 16 + lr];
        const float bg = gb[nt * 16 + lr];
        f32x4 ao[2] = {f32x4{bo, bo, bo, bo}, f32x4{bo, bo, bo, bo}};
        f32x4 ag[2] = {f32x4{bg, bg, bg, bg}, f32x4{bg, bg, bg, bg}};
        #pragma unroll
        for (int ks = 0; ks < 8; ++ks) {
            const int kb = ks * 32 + lg * 8;
            const short8 b_o  = *reinterpret_cast<const short8*>(
                &wsb[(size_t)(POW + ((nt * 8 + ks) * 64 + lane) * 8)]);
            const short8 b_g1 = *reinterpret_cast<const short8*>(
                &wsb[(size_t)(PGW + ((nt * 16 + ks) * 64 + lane) * 8)]);
            const short8 b_g2 = *reinterpret_cast<const short8*>(
                &wsb[(size_t)(PGW + ((nt * 16 + ks + 8) * 64 + lane) * 8)]);
            #pragma unroll
            for (int m = 0; m < 2; ++m) {
                const short8 aa = *reinterpret_cast<const short8*>(&s_ab[m * 16 + lr][kb]);
                const short8 ah = *reinterpret_cast<const short8*>(&s_hb[m * 16 + lr][kb]);
                ao[m] = __builtin_amdgcn_mfma_f32_16x16x32_bf16(aa, b_o,  ao[m], 0, 0, 0);
                ag[m] = __builtin_amdgcn_mfma_f32_16x16x32_bf16(ah, b_g1, ag[m], 0, 0, 0);
                ag[m] = __builtin_amdgcn_mfma_f32_16x16x32_bf16(aa, b_g2, ag[m], 0, 0, 0);
            }
        }
        #pragma unroll
        for (int m = 0; m < 2; ++m) {
            const int col = nt * 16 + lr;
            #pragma unroll
            for (int q = 0; q < 4; ++q) {
                const int row = m0 + m * 16 + 4 * lg + q;
                const float g = 1.f / (1.f + __expf(-ag[m][q]));
                out[(size_t)row * ND + col] = g * ao[m][q];
            }
        }
    }
}

// ---------------------------------------------------------------------------
// fallback: proven f32 kernel (used only if ws_size < WS_NEED)
// ---------------------------------------------------------------------------
__global__ __launch_bounds__(512, 2)
void stk_fused(const float* __restrict__ h,
               const int*   __restrict__ topk_idx,
               const float* __restrict__ topk_scores,
               const float* __restrict__ vW, const float* __restrict__ vb,
               const float* __restrict__ oW, const float* __restrict__ ob,
               const float* __restrict__ gW, const float* __restrict__ gb,
               float* __restrict__ out)
{
    __shared__ float s_attn[32][NK];
    __shared__ int   s_idx [32][NK];
    __shared__ float s_wsum[32][ND];
    __shared__ float s_h   [32][ND];
    __shared__ float s_agg [32][ND];

    const int t  = threadIdx.x;
    const int m0 = blockIdx.x * 32;
    const size_t hb = (size_t)(m0 >> 9) * NC * ND;

    {
        const int k  = t & 31;
        const int r0 = t >> 5;
        #pragma unroll
        for (int half = 0; half < 2; ++half) {
            const int r = r0 + (half << 4);
            const size_t off = (size_t)(m0 + r) * NK + k;
            const float s = topk_scores[off];
            const int  id = topk_idx[off];
            float m = s;
            #pragma unroll
            for (int msk = 16; msk >= 1; msk >>= 1) m = fmaxf(m, __shfl_xor(m, msk));
            const float p = __expf(s - m);
            float Z = p;
            #pragma unroll
            for (int msk = 16; msk >= 1; msk >>= 1) Z += __shfl_xor(Z, msk);
            s_attn[r][k] = p / Z;
            s_idx [r][k] = id;
        }
    }
    __syncthreads();

    const int d  = t & 127;
    const int rb = (t >> 7) * 8;

    #pragma unroll
    for (int i = 0; i < 8; ++i) {
        const int r = rb + i;
        const size_t ro = (size_t)(m0 + r) * ND;
        s_h[r][d]       = h[ro + d];
        s_h[r][d + 128] = h[ro + d + 128];
    }
    #pragma unroll 1
    for (int i = 0; i < 8; ++i) {
        const int r = rb + i;
        float a0 = 0.f, a1 = 0.f;
        #pragma unroll 8
        for (int k = 0; k < NK; ++k) {
            const float w  = s_attn[r][k];
            const size_t nb = hb + (size_t)s_idx[r][k] * ND;
            a0 = fmaf(w, h[nb + d],       a0);
            a1 = fmaf(w, h[nb + d + 128], a1);
        }
        s_wsum[r][d]       = a0;
        s_wsum[r][d + 128] = a1;
    }
    __syncthreads();

    float agg0[8], agg1[8];
    {
        const float b0 = vb[d], b1 = vb[d + 128];
        #pragma unroll
        for (int i = 0; i < 8; ++i) { agg0[i] = b0; agg1[i] = b1; }
        for (int e0 = 0; e0 < ND; e0 += 4) {
            float w0[4], w1[4];
            #pragma unroll
            for (int j = 0; j < 4; ++j) {
                w0[j] = vW[(size_t)(e0 + j) * ND + d];
                w1[j] = vW[(size_t)(e0 + j) * ND + d + 128];
            }
            #pragma unroll
            for (int i = 0; i < 8; ++i) {
                const float4 a = *reinterpret_cast<const float4*>(&s_wsum[rb + i][e0]);
                agg0[i] = fmaf(a.x, w0[0], agg0[i]); agg1[i] = fmaf(a.x, w1[0], agg1[i]);
                agg0[i] = fmaf(a.y, w0[1], agg0[i]); agg1[i] = fmaf(a.y, w1[1], agg1[i]);
                agg0[i] = fmaf(a.z, w0[2], agg0[i]); agg1[i] = fmaf(a.z, w1[2], agg1[i]);
                agg0[i] = fmaf(a.w, w0[3], agg0[i]); agg1[i] = fmaf(a.w, w1[3], agg1[i]);
            }
        }
        #pragma unroll
        for (int i = 0; i < 8; ++i) {
            s_agg[rb + i][d]       = agg0[i];
            s_agg[rb + i][d + 128] = agg1[i];
        }
    }
    __syncthreads();

    float o0[8], o1[8], g0[8], g1[8];
    {
        const float obb0 = ob[d], obb1 = ob[d + 128];
        const float gbb0 = gb[d], gbb1 = gb[d + 128];
        #pragma unroll
        for (int i = 0; i < 8; ++i) { o0[i]=obb0; o1[i]=obb1; g0[i]=gbb0; g1[i]=gbb1; }
        for (int e0 = 0; e0 < ND; e0 += 4) {
            float ow0[4], ow1[4], gh0[4], gh1[4], ga0[4], ga1[4];
            #pragma unroll
            for (int j = 0; j < 4; ++j) {
                const size_t er = (size_t)(e0 + j) * ND;
                ow0[j] = oW[er + d];                    ow1[j] = oW[er + d + 128];
                gh0[j] = gW[er + d];                    gh1[j] = gW[er + d + 128];
                ga0[j] = gW[er + (size_t)ND * ND + d];  ga1[j] = gW[er + (size_t)ND * ND + d + 128];
            }
            #pragma unroll
            for (int i = 0; i < 8; ++i) {
                const float4 a  = *reinterpret_cast<const float4*>(&s_agg[rb + i][e0]);
                const float4 hh = *reinterpret_cast<const float4*>(&s_h  [rb + i][e0]);
                o0[i] = fmaf(a.x, ow0[0], o0[i]); o0[i] = fmaf(a.y, ow0[1], o0[i]);
                o0[i] = fmaf(a.z, ow0[2], o0[i]); o0[i] = fmaf(a.w, ow0[3], o0[i]);
                o1[i] = fmaf(a.x, ow1[0], o1[i]); o1[i] = fmaf(a.y, ow1[1], o1[i]);
                o1[i] = fmaf(a.z, ow1[2], o1[i]); o1[i] = fmaf(a.w, ow1[3], o1[i]);
                g0[i] = fmaf(hh.x, gh0[0], g0[i]); g0[i] = fmaf(hh.y, gh0[1], g0[i]);
                g0[i] = fmaf(hh.z, gh0[2], g0[i]); g0[i] = fmaf(hh.w, gh0[3], g0[i]);
                g1[i] = fmaf(hh.x, gh1[0], g1[i]); g1[i] = fmaf(hh.y, gh1[1], g1[i]);
                g1[i] = fmaf(hh.z, gh1[2], g1[i]); g1[i] = fmaf(hh.w, gh1[3], g1[i]);
                g0[i] = fmaf(a.x, ga0[0], g0[i]); g0[i] = fmaf(a.y, ga0[1], g0[i]);
                g0[i] = fmaf(a.z, ga0[2], g0[i]); g0[i] = fmaf(a.w, ga0[3], g0[i]);
                g1[i] = fmaf(a.x, ga1[0], g1[i]); g1[i] = fmaf(a.y, ga1[1], g1[i]);
                g1[i] = fmaf(a.z, ga1[2], g1[i]); g1[i] = fmaf(a.w, ga1[3], g1[i]);
            }
        }
    }
    #pragma unroll
    for (int i = 0; i < 8; ++i) {
        const size_t ro = (size_t)(m0 + rb + i) * ND;
        const float sg0 = 1.f / (1.f + __expf(-g0[i]));
        const float sg1 = 1.f / (1.f + __expf(-g1[i]));
        out[ro + d]       = sg0 * o0[i];
        out[ro + d + 128] = sg1 * o1[i];
    }
}

extern "C" void kernel_launch(void* const* d_in, const int* in_sizes, int n_in,
                              void* d_out, int out_size, void* d_ws, size_t ws_size,
                              hipStream_t stream) {
    const float* h   = (const float*)d_in[0];
    const int*   idx = (const int*)  d_in[1];
    const float* sc  = (const float*)d_in[2];
    const float* vW  = (const float*)d_in[3];
    const float* vb  = (const float*)d_in[4];
    const float* oW  = (const float*)d_in[5];
    const float* ob  = (const float*)d_in[6];
    const float* gW  = (const float*)d_in[7];
    const float* gb  = (const float*)d_in[8];
    float* out = (float*)d_out;

    if (ws_size >= WS_NEED) {
        unsigned short* wsb = (unsigned short*)d_ws;
        stk_pack_all<<<1152, 256, 0, stream>>>(vW, oW, gW, h, wsb);
        stk_mfma    <<<NBLK, NTHR, 0, stream>>>(h, idx, sc, vb, ob, gb, wsb, out);
    } else {
        stk_fused<<<256, 512, 0, stream>>>(h, idx, sc, vW, vb, oW, ob, gW, gb, out);
    }
}

// Round 8
// 32.523 us; speedup vs baseline: 1.0273x; 1.0273x over previous
//
#include <hip/hip_runtime.h>
#include <hip/hip_bf16.h>
#include <cstdint>
#include <cstddef>

using short8  = __attribute__((ext_vector_type(8))) short;
using short4v = __attribute__((ext_vector_type(4))) short;
using f32x4   = __attribute__((ext_vector_type(4))) float;

constexpr int NB = 16, NC = 512, ND = 256, NK = 32;
constexpr int ROWS = 32;               // rows per block in fused kernel
constexpr int NROW = NB * NC;          // 8192
constexpr int NBLK = NROW / ROWS;      // 256
constexpr int LDP  = ND + 8;           // ushort row stride (528 B)
constexpr int PLD  = 516;              // P f32 row stride

// fused-kernel LDS: P f32 [32][516] (66048 B), s_ab bf16 [32][528] unioned in
constexpr int LDS_TOT = ROWS * PLD * 4;            // 66048 -> 2 blocks/CU

// d_ws layout (bf16 element offsets):
//  oW  frags [0, 65536):      fl = nt*8+ks, elem=(fl*64+lane)*8+j = oW[ks*32+(lane>>4)*8+j][nt*16+(lane&15)]
//  gWa frags [65536, 131072): same, src rows 256..511 of gW
//  gh C-frags [131072, +2097152): mt=global 16-row tile (0..511):
//     elem = PGH + ((mt*16+nt)*64+lane)*4+qq = gh[mt*16+4*(lane>>4)+qq][nt*16+(lane&15)]
//  hv B-frags [PHV, +2097152): per batch b, frag ksc*16+nt:
//     elem = PHV + b*131072 + ((ksc*16+nt)*64+lane)*8+j = hv[b][ksc*32+(lane>>4)*8+j][nt*16+(lane&15)]
constexpr int POW2 = 0;
constexpr int PGA  = 65536;
constexpr int PGH  = 131072;
constexpr int PHV  = 131072 + 2097152;             // 2228224
constexpr size_t WS_NEED = (size_t)(PHV + NB * 131072) * 2;  // 8.65 MB (ws ~256 MB)

static __device__ __forceinline__ unsigned short f2bf(float f) {
    __hip_bfloat16 b = __float2bfloat16(f);
    return *reinterpret_cast<unsigned short*>(&b);
}
static __device__ __forceinline__ float bf2f(unsigned short u) {
    return __uint_as_float(((unsigned)u) << 16);
}
static __device__ __forceinline__ short4v f2bf4(float4 v) {
    short4v r;
    r[0] = (short)f2bf(v.x); r[1] = (short)f2bf(v.y);
    r[2] = (short)f2bf(v.z); r[3] = (short)f2bf(v.w);
    return r;
}

// ---------------------------------------------------------------------------
// prep: blocks 0..31 pack oW/gW_a frags; blocks 32..287 compute hv & gh tiles
//   hv = h@vW + vb  (B-frag layout, per batch)
//   gh = h@gW_h + gb (C-frag layout, per 16-row tile)
// ---------------------------------------------------------------------------
__global__ __launch_bounds__(512)
void stk_prep(const float* __restrict__ vW, const float* __restrict__ vb,
              const float* __restrict__ oW,
              const float* __restrict__ gW, const float* __restrict__ gb,
              const float* __restrict__ h, unsigned short* __restrict__ ws)
{
    __shared__ __align__(16) unsigned short s_a[32][264];   // h tile bf16
    __shared__ __align__(16) unsigned short s_c[32][264];   // hv tile bf16
    const int blk = blockIdx.x;
    const int t   = threadIdx.x;

    if (blk < 32) {               // ---- weight fragment packing ----
        const int tid  = blk * 512 + t;        // 16384 threads
        const int lane = tid & 63;
        const int fl   = tid >> 6;             // 0..255
        const float* src; int nt, ks, rowoff; size_t dst;
        if (fl < 128) { src = oW; nt = fl >> 3; ks = fl & 7; rowoff = 0;
                        dst = (size_t)POW2 + (size_t)fl * 512; }
        else { const int f2 = fl - 128; src = gW; nt = f2 >> 3; ks = f2 & 7; rowoff = 256;
               dst = (size_t)PGA + (size_t)f2 * 512; }
        const int col = nt * 16 + (lane & 15);
        const int k0  = rowoff + ks * 32 + (lane >> 4) * 8;
        short8 v;
        #pragma unroll
        for (int j = 0; j < 8; ++j)
            v[j] = (short)f2bf(src[(size_t)(k0 + j) * ND + col]);
        *reinterpret_cast<short8*>(&ws[dst + (size_t)lane * 8]) = v;
        return;
    }

    // ---- per-tile GEMMs: batch b, row-tile rt (32 rows) ----
    const int q  = blk - 32;                   // 0..255
    const int b  = q >> 4, rt = q & 15;
    const float* hb = h + ((size_t)b * NC + rt * 32) * ND;

    {   // stage h tile [32][256] -> bf16 LDS
        const int row = t >> 4;                // 0..31
        const int c0  = (t & 15) * 16;
        #pragma unroll
        for (int u = 0; u < 4; ++u) {
            const float4 x = *reinterpret_cast<const float4*>(&hb[(size_t)row * ND + c0 + 4 * u]);
            *reinterpret_cast<short4v*>(&s_a[row][c0 + 4 * u]) = f2bf4(x);
        }
    }
    __syncthreads();

    const int lane = t & 63, w = t >> 6;       // 8 waves
    const int lr = lane & 15, lg = lane >> 4;
    const int n0 = 2 * w;

    f32x4 ahv[2][2], agh[2][2];
    #pragma unroll
    for (int n = 0; n < 2; ++n) {
        const float bvv = vb[(n0 + n) * 16 + lr];
        const float bgg = gb[(n0 + n) * 16 + lr];
        #pragma unroll
        for (int m = 0; m < 2; ++m) {
            ahv[m][n] = f32x4{bvv, bvv, bvv, bvv};
            agh[m][n] = f32x4{bgg, bgg, bgg, bgg};
        }
    }
    #pragma unroll
    for (int ks = 0; ks < 8; ++ks) {
        const int kb = ks * 32 + lg * 8;
        const short8 a0 = *reinterpret_cast<const short8*>(&s_a[lr][kb]);
        const short8 a1 = *reinterpret_cast<const short8*>(&s_a[16 + lr][kb]);
        #pragma unroll
        for (int n = 0; n < 2; ++n) {
            const int col = (n0 + n) * 16 + lr;
            short8 bv, bg;
            #pragma unroll
            for (int j = 0; j < 8; ++j) {
                bv[j] = (short)f2bf(vW[(size_t)(kb + j) * ND + col]);
                bg[j] = (short)f2bf(gW[(size_t)(kb + j) * ND + col]);   // gW_h rows 0..255
            }
            ahv[0][n] = __builtin_amdgcn_mfma_f32_16x16x32_bf16(a0, bv, ahv[0][n], 0, 0, 0);
            ahv[1][n] = __builtin_amdgcn_mfma_f32_16x16x32_bf16(a1, bv, ahv[1][n], 0, 0, 0);
            agh[0][n] = __builtin_amdgcn_mfma_f32_16x16x32_bf16(a0, bg, agh[0][n], 0, 0, 0);
            agh[1][n] = __builtin_amdgcn_mfma_f32_16x16x32_bf16(a1, bg, agh[1][n], 0, 0, 0);
        }
    }
    // gh: store directly in C-frag layout
    #pragma unroll
    for (int m = 0; m < 2; ++m)
        #pragma unroll
        for (int n = 0; n < 2; ++n) {
            const int mt = b * 32 + rt * 2 + m;
            short4v v4;
            #pragma unroll
            for (int qq = 0; qq < 4; ++qq) v4[qq] = (short)f2bf(agh[m][n][qq]);
            *reinterpret_cast<short4v*>(
                &ws[(size_t)PGH + ((size_t)(mt * 16 + n0 + n) * 64 + lane) * 4]) = v4;
        }
    // hv: stage C to LDS, then write out in B-frag layout (ksc = rt)
    #pragma unroll
    for (int m = 0; m < 2; ++m)
        #pragma unroll
        for (int n = 0; n < 2; ++n)
            #pragma unroll
            for (int qq = 0; qq < 4; ++qq)
                s_c[m * 16 + 4 * lg + qq][(n0 + n) * 16 + lr] = f2bf(ahv[m][n][qq]);
    __syncthreads();
    #pragma unroll
    for (int n = 0; n < 2; ++n) {
        const int nt = n0 + n;
        short8 v;
        #pragma unroll
        for (int j = 0; j < 8; ++j)
            v[j] = (short)s_c[lg * 8 + j][nt * 16 + lr];
        *reinterpret_cast<short8*>(
            &ws[(size_t)PHV + (size_t)b * 131072 + ((size_t)(rt * 16 + nt) * 64 + lane) * 8]) = v;
    }
}

// ---------------------------------------------------------------------------
// fused kernel: 32 rows/block, 512 threads (8 waves), 2 blocks/CU
// ---------------------------------------------------------------------------
__global__ __launch_bounds__(512, 4)
void stk_main(const int*   __restrict__ topk_idx,
              const float* __restrict__ topk_scores,
              const float* __restrict__ ob,
              const unsigned short* __restrict__ wsb,
              float* __restrict__ out)
{
    __shared__ __align__(16) char smem[LDS_TOT];
    float          (*s_P )[PLD] = reinterpret_cast<float(*)[PLD]>(smem);
    unsigned short (*s_ab)[LDP] = reinterpret_cast<unsigned short(*)[LDP]>(smem); // union

    const int t   = threadIdx.x;
    // XCD swizzle: 256 blocks -> 32 consecutive tiles (2 batches) per XCD
    const int bid = (int)blockIdx.x;
    const int swz = ((bid & 7) << 5) + (bid >> 3);
    const int m0  = swz * ROWS;
    const int batch = m0 >> 9;

    // ---- zero P (32*516/4 = 4128 float4) -----------------------------------
    {
        float4* p4 = reinterpret_cast<float4*>(smem);
        #pragma unroll
        for (int i = 0; i < 9; ++i) {
            const int j = t + i * 512;
            if (j < (ROWS * PLD) / 4) p4[j] = float4{0.f, 0.f, 0.f, 0.f};
        }
    }

    // ---- softmax over K, two rows per thread (width-32 butterflies) --------
    const int k  = t & 31;
    const int r0 = t >> 5;                // 0..15
    float att[2]; int id[2];
    #pragma unroll
    for (int half = 0; half < 2; ++half) {
        const int r = r0 + (half << 4);
        const size_t off = (size_t)(m0 + r) * NK + k;
        const float s = topk_scores[off];
        id[half] = topk_idx[off];
        float m = s;
        #pragma unroll
        for (int msk = 16; msk >= 1; msk >>= 1)
            m = fmaxf(m, __shfl_xor(m, msk));
        const float p = __expf(s - m);
        float Z = p;
        #pragma unroll
        for (int msk = 16; msk >= 1; msk >>= 1)
            Z += __shfl_xor(Z, msk);
        att[half] = p / Z;
    }
    __syncthreads();                      // P zeroed

    atomicAdd(&s_P[r0][id[0]],      att[0]);
    atomicAdd(&s_P[r0 + 16][id[1]], att[1]);
    __syncthreads();                      // P complete

    const int lane = t & 63, w = t >> 6;  // 8 waves
    const int n0 = 2 * w, lr = lane & 15, lg = lane >> 4;

    // ---- GEMM1: agg = P @ hv (vb folded into hv; P rows sum to 1) ----------
    f32x4 acc[2][2] = {{f32x4{0,0,0,0}, f32x4{0,0,0,0}},
                       {f32x4{0,0,0,0}, f32x4{0,0,0,0}}};
    {
        const unsigned short* hf = wsb + (size_t)PHV + (size_t)batch * 131072;
        #pragma unroll
        for (int ks = 0; ks < 16; ++ks) {
            const int kb = ks * 32 + lg * 8;
            short8 a[2];
            #pragma unroll
            for (int m = 0; m < 2; ++m) {
                const float4 x0 = *reinterpret_cast<const float4*>(&s_P[m * 16 + lr][kb]);
                const float4 x1 = *reinterpret_cast<const float4*>(&s_P[m * 16 + lr][kb + 4]);
                a[m][0] = (short)f2bf(x0.x); a[m][1] = (short)f2bf(x0.y);
                a[m][2] = (short)f2bf(x0.z); a[m][3] = (short)f2bf(x0.w);
                a[m][4] = (short)f2bf(x1.x); a[m][5] = (short)f2bf(x1.y);
                a[m][6] = (short)f2bf(x1.z); a[m][7] = (short)f2bf(x1.w);
            }
            #pragma unroll
            for (int n = 0; n < 2; ++n) {
                const short8 bfr = *reinterpret_cast<const short8*>(
                    &hf[((size_t)(ks * 16 + n0 + n) * 64 + lane) * 8]);
                acc[0][n] = __builtin_amdgcn_mfma_f32_16x16x32_bf16(a[0], bfr, acc[0][n], 0, 0, 0);
                acc[1][n] = __builtin_amdgcn_mfma_f32_16x16x32_bf16(a[1], bfr, acc[1][n], 0, 0, 0);
            }
        }
    }
    __syncthreads();                      // all P reads done before union overwrite

    #pragma unroll
    for (int m = 0; m < 2; ++m)
        #pragma unroll
        for (int n = 0; n < 2; ++n)
            #pragma unroll
            for (int qq = 0; qq < 4; ++qq)
                s_ab[m * 16 + 4 * lg + qq][(n0 + n) * 16 + lr] = f2bf(acc[m][n][qq]);
    __syncthreads();                      // agg tile ready

    // ---- GEMM3: o = agg@oW + ob ; g = gh + agg@gW_a ; epilogue -------------
    {
        f32x4 ao[2][2], ag[2][2];
        #pragma unroll
        for (int n = 0; n < 2; ++n) {
            const float bo = ob[(n0 + n) * 16 + lr];
            #pragma unroll
            for (int m = 0; m < 2; ++m) ao[m][n] = f32x4{bo, bo, bo, bo};
        }
        #pragma unroll
        for (int m = 0; m < 2; ++m)
            #pragma unroll
            for (int n = 0; n < 2; ++n) {
                const int mt = swz * 2 + m;
                const short4v g4 = *reinterpret_cast<const short4v*>(
                    &wsb[(size_t)PGH + ((size_t)(mt * 16 + n0 + n) * 64 + lane) * 4]);
                #pragma unroll
                for (int qq = 0; qq < 4; ++qq)
                    ag[m][n][qq] = bf2f((unsigned short)g4[qq]);
            }
        #pragma unroll
        for (int ks = 0; ks < 8; ++ks) {
            const int kb = ks * 32 + lg * 8;
            short8 aa[2];
            #pragma unroll
            for (int m = 0; m < 2; ++m)
                aa[m] = *reinterpret_cast<const short8*>(&s_ab[m * 16 + lr][kb]);
            #pragma unroll
            for (int n = 0; n < 2; ++n) {
                const int nt = n0 + n;
                const short8 bo8 = *reinterpret_cast<const short8*>(
                    &wsb[(size_t)POW2 + ((size_t)(nt * 8 + ks) * 64 + lane) * 8]);
                const short8 bg8 = *reinterpret_cast<const short8*>(
                    &wsb[(size_t)PGA + ((size_t)(nt * 8 + ks) * 64 + lane) * 8]);
                #pragma unroll
                for (int m = 0; m < 2; ++m) {
                    ao[m][n] = __builtin_amdgcn_mfma_f32_16x16x32_bf16(aa[m], bo8, ao[m][n], 0, 0, 0);
                    ag[m][n] = __builtin_amdgcn_mfma_f32_16x16x32_bf16(aa[m], bg8, ag[m][n], 0, 0, 0);
                }
            }
        }
        #pragma unroll
        for (int m = 0; m < 2; ++m)
            #pragma unroll
            for (int n = 0; n < 2; ++n) {
                const int col = (n0 + n) * 16 + lr;
                #pragma unroll
                for (int qq = 0; qq < 4; ++qq) {
                    const int row = m0 + m * 16 + 4 * lg + qq;
                    const float g = 1.f / (1.f + __expf(-ag[m][n][qq]));
                    out[(size_t)row * ND + col] = g * ao[m][n][qq];
                }
            }
    }
}

// ---------------------------------------------------------------------------
// fallback: proven f32 kernel (used only if ws_size < WS_NEED)
// ---------------------------------------------------------------------------
__global__ __launch_bounds__(512, 2)
void stk_fused(const float* __restrict__ h,
               const int*   __restrict__ topk_idx,
               const float* __restrict__ topk_scores,
               const float* __restrict__ vW, const float* __restrict__ vb,
               const float* __restrict__ oW, const float* __restrict__ ob,
               const float* __restrict__ gW, const float* __restrict__ gb,
               float* __restrict__ out)
{
    __shared__ float s_attn[32][NK];
    __shared__ int   s_idx [32][NK];
    __shared__ float s_wsum[32][ND];
    __shared__ float s_h   [32][ND];
    __shared__ float s_agg [32][ND];

    const int t  = threadIdx.x;
    const int m0 = blockIdx.x * 32;
    const size_t hb = (size_t)(m0 >> 9) * NC * ND;

    {
        const int k  = t & 31;
        const int r0 = t >> 5;
        #pragma unroll
        for (int half = 0; half < 2; ++half) {
            const int r = r0 + (half << 4);
            const size_t off = (size_t)(m0 + r) * NK + k;
            const float s = topk_scores[off];
            const int  id = topk_idx[off];
            float m = s;
            #pragma unroll
            for (int msk = 16; msk >= 1; msk >>= 1) m = fmaxf(m, __shfl_xor(m, msk));
            const float p = __expf(s - m);
            float Z = p;
            #pragma unroll
            for (int msk = 16; msk >= 1; msk >>= 1) Z += __shfl_xor(Z, msk);
            s_attn[r][k] = p / Z;
            s_idx [r][k] = id;
        }
    }
    __syncthreads();

    const int d  = t & 127;
    const int rb = (t >> 7) * 8;

    #pragma unroll
    for (int i = 0; i < 8; ++i) {
        const int r = rb + i;
        const size_t ro = (size_t)(m0 + r) * ND;
        s_h[r][d]       = h[ro + d];
        s_h[r][d + 128] = h[ro + d + 128];
    }
    #pragma unroll 1
    for (int i = 0; i < 8; ++i) {
        const int r = rb + i;
        float a0 = 0.f, a1 = 0.f;
        #pragma unroll 8
        for (int k = 0; k < NK; ++k) {
            const float w  = s_attn[r][k];
            const size_t nb = hb + (size_t)s_idx[r][k] * ND;
            a0 = fmaf(w, h[nb + d],       a0);
            a1 = fmaf(w, h[nb + d + 128], a1);
        }
        s_wsum[r][d]       = a0;
        s_wsum[r][d + 128] = a1;
    }
    __syncthreads();

    float agg0[8], agg1[8];
    {
        const float b0 = vb[d], b1 = vb[d + 128];
        #pragma unroll
        for (int i = 0; i < 8; ++i) { agg0[i] = b0; agg1[i] = b1; }
        for (int e0 = 0; e0 < ND; e0 += 4) {
            float w0[4], w1[4];
            #pragma unroll
            for (int j = 0; j < 4; ++j) {
                w0[j] = vW[(size_t)(e0 + j) * ND + d];
                w1[j] = vW[(size_t)(e0 + j) * ND + d + 128];
            }
            #pragma unroll
            for (int i = 0; i < 8; ++i) {
                const float4 a = *reinterpret_cast<const float4*>(&s_wsum[rb + i][e0]);
                agg0[i] = fmaf(a.x, w0[0], agg0[i]); agg1[i] = fmaf(a.x, w1[0], agg1[i]);
                agg0[i] = fmaf(a.y, w0[1], agg0[i]); agg1[i] = fmaf(a.y, w1[1], agg1[i]);
                agg0[i] = fmaf(a.z, w0[2], agg0[i]); agg1[i] = fmaf(a.z, w1[2], agg1[i]);
                agg0[i] = fmaf(a.w, w0[3], agg0[i]); agg1[i] = fmaf(a.w, w1[3], agg1[i]);
            }
        }
        #pragma unroll
        for (int i = 0; i < 8; ++i) {
            s_agg[rb + i][d]       = agg0[i];
            s_agg[rb + i][d + 128] = agg1[i];
        }
    }
    __syncthreads();

    float o0[8], o1[8], g0[8], g1[8];
    {
        const float obb0 = ob[d], obb1 = ob[d + 128];
        const float gbb0 = gb[d], gbb1 = gb[d + 128];
        #pragma unroll
        for (int i = 0; i < 8; ++i) { o0[i]=obb0; o1[i]=obb1; g0[i]=gbb0; g1[i]=gbb1; }
        for (int e0 = 0; e0 < ND; e0 += 4) {
            float ow0[4], ow1[4], gh0[4], gh1[4], ga0[4], ga1[4];
            #pragma unroll
            for (int j = 0; j < 4; ++j) {
                const size_t er = (size_t)(e0 + j) * ND;
                ow0[j] = oW[er + d];                    ow1[j] = oW[er + d + 128];
                gh0[j] = gW[er + d];                    gh1[j] = gW[er + d + 128];
                ga0[j] = gW[er + (size_t)ND * ND + d];  ga1[j] = gW[er + (size_t)ND * ND + d + 128];
            }
            #pragma unroll
            for (int i = 0; i < 8; ++i) {
                const float4 a  = *reinterpret_cast<const float4*>(&s_agg[rb + i][e0]);
                const float4 hh = *reinterpret_cast<const float4*>(&s_h  [rb + i][e0]);
                o0[i] = fmaf(a.x, ow0[0], o0[i]); o0[i] = fmaf(a.y, ow0[1], o0[i]);
                o0[i] = fmaf(a.z, ow0[2], o0[i]); o0[i] = fmaf(a.w, ow0[3], o0[i]);
                o1[i] = fmaf(a.x, ow1[0], o1[i]); o1[i] = fmaf(a.y, ow1[1], o1[i]);
                o1[i] = fmaf(a.z, ow1[2], o1[i]); o1[i] = fmaf(a.w, ow1[3], o1[i]);
                g0[i] = fmaf(hh.x, gh0[0], g0[i]); g0[i] = fmaf(hh.y, gh0[1], g0[i]);
                g0[i] = fmaf(hh.z, gh0[2], g0[i]); g0[i] = fmaf(hh.w, gh0[3], g0[i]);
                g1[i] = fmaf(hh.x, gh1[0], g1[i]); g1[i] = fmaf(hh.y, gh1[1], g1[i]);
                g1[i] = fmaf(hh.z, gh1[2], g1[i]); g1[i] = fmaf(hh.w, gh1[3], g1[i]);
                g0[i] = fmaf(a.x, ga0[0], g0[i]); g0[i] = fmaf(a.y, ga0[1], g0[i]);
                g0[i] = fmaf(a.z, ga0[2], g0[i]); g0[i] = fmaf(a.w, ga0[3], g0[i]);
                g1[i] = fmaf(a.x, ga1[0], g1[i]); g1[i] = fmaf(a.y, ga1[1], g1[i]);
                g1[i] = fmaf(a.z, ga1[2], g1[i]); g1[i] = fmaf(a.w, ga1[3], g1[i]);
            }
        }
    }
    #pragma unroll
    for (int i = 0; i < 8; ++i) {
        const size_t ro = (size_t)(m0 + rb + i) * ND;
        const float sg0 = 1.f / (1.f + __expf(-g0[i]));
        const float sg1 = 1.f / (1.f + __expf(-g1[i]));
        out[ro + d]       = sg0 * o0[i];
        out[ro + d + 128] = sg1 * o1[i];
    }
}

extern "C" void kernel_launch(void* const* d_in, const int* in_sizes, int n_in,
                              void* d_out, int out_size, void* d_ws, size_t ws_size,
                              hipStream_t stream) {
    const float* h   = (const float*)d_in[0];
    const int*   idx = (const int*)  d_in[1];
    const float* sc  = (const float*)d_in[2];
    const float* vW  = (const float*)d_in[3];
    const float* vb  = (const float*)d_in[4];
    const float* oW  = (const float*)d_in[5];
    const float* ob  = (const float*)d_in[6];
    const float* gW  = (const float*)d_in[7];
    const float* gb  = (const float*)d_in[8];
    float* out = (float*)d_out;

    if (ws_size >= WS_NEED) {
        unsigned short* wsb = (unsigned short*)d_ws;
        stk_prep<<<288,  512, 0, stream>>>(vW, vb, oW, gW, gb, h, wsb);
        stk_main<<<NBLK, 512, 0, stream>>>(idx, sc, ob, wsb, out);
    } else {
        stk_fused<<<256, 512, 0, stream>>>(h, idx, sc, vW, vb, oW, ob, gW, gb, out);
    }
}

// Round 9
// 28.704 us; speedup vs baseline: 1.1640x; 1.1331x over previous
//
#include <hip/hip_runtime.h>
#include <hip/hip_bf16.h>
#include <cstdint>
#include <cstddef>

using short8  = __attribute__((ext_vector_type(8))) short;
using short4v = __attribute__((ext_vector_type(4))) short;
using f32x4   = __attribute__((ext_vector_type(4))) float;

constexpr int NB = 16, NC = 512, ND = 256, NK = 32;
constexpr int ROWS = 32;               // rows per block
constexpr int NROW = NB * NC;          // 8192
constexpr int NBLK = NROW / ROWS;      // 256
constexpr int NTHR = 512;              // 8 waves

// single 64 KB LDS region, repartitioned over time:
//  phase 1: P f32 [32][512]                      (65536 B)
//  phase 2: Pb bf16 [32][512] swz  @ 0           (32768 B)
//           s_w bf16 [32][256] swz @ 32768       (16384 B)
//           s_hb bf16 [32][256] swz @ 49152      (16384 B)
//  phase 3: s_ab bf16 [32][256] swz @ 0 (over dead Pb)
constexpr int OFF_SW = 32768;
constexpr int OFF_HB = 49152;

// d_ws layout (bf16 element offsets) — identical to R6 (verified):
//  vW frags [0,65536): fl=nt*8+ks ; oW [65536,131072) ; gW [131072,262144): fl=nt*16+ks
//  h  frags [262144 + b*131072): frag fs=ks*16+nt
constexpr int PVW = 0;
constexpr int POW = 65536;
constexpr int PGW = 131072;
constexpr int PHB = 262144;
constexpr size_t WS_NEED = (size_t)(PHB + NB * 131072) * 2;   // ~4.7 MB

static __device__ __forceinline__ unsigned short f2bf(float f) {
    __hip_bfloat16 b = __float2bfloat16(f);
    return *reinterpret_cast<unsigned short*>(&b);
}
static __device__ __forceinline__ short4v f2bf4(float4 v) {
    short4v r;
    r[0] = (short)f2bf(v.x); r[1] = (short)f2bf(v.y);
    r[2] = (short)f2bf(v.z); r[3] = (short)f2bf(v.w);
    return r;
}

// ---------------------------------------------------------------------------
// merged pack (R6 verbatim): blocks 0..127 weights; 128..1151 h slabs
// ---------------------------------------------------------------------------
__global__ __launch_bounds__(256)
void stk_pack_all(const float* __restrict__ vW, const float* __restrict__ oW,
                  const float* __restrict__ gW, const float* __restrict__ h,
                  unsigned short* __restrict__ ws)
{
    const int blk = blockIdx.x;
    if (blk < 128) {
        const int tid  = blk * 256 + threadIdx.x;      // 32768 threads
        const int lane = tid & 63;
        const int fl   = tid >> 6;                     // 0..511
        const float* src; int nt, ks;
        if (fl < 128)      { src = vW; nt = fl >> 3;         ks = fl & 7;          }
        else if (fl < 256) { src = oW; nt = (fl - 128) >> 3; ks = (fl - 128) & 7;  }
        else               { src = gW; nt = (fl - 256) >> 4; ks = (fl - 256) & 15; }
        const int col = nt * 16 + (lane & 15);
        const int k0  = ks * 32 + (lane >> 4) * 8;
        short8 v;
        #pragma unroll
        for (int j = 0; j < 8; ++j)
            v[j] = (short)f2bf(src[(size_t)(k0 + j) * ND + col]);
        *reinterpret_cast<short8*>(&ws[(size_t)tid * 8]) = v;
    } else {
        const int tid  = (blk - 128) * 256 + threadIdx.x;   // 262144 threads
        const int lane = tid & 63;
        const int fs   = tid >> 6;                     // b*256 + ks*16 + nt
        const int b    = fs >> 8;
        const int ks   = (fs >> 4) & 15;
        const int nt   = fs & 15;
        const float* src = h + (size_t)b * NC * ND;
        const int col = nt * 16 + (lane & 15);
        const int k0  = ks * 32 + (lane >> 4) * 8;
        short8 v;
        #pragma unroll
        for (int j = 0; j < 8; ++j)
            v[j] = (short)f2bf(src[(size_t)(k0 + j) * ND + col]);
        *reinterpret_cast<short8*>(&ws[(size_t)PHB + (size_t)tid * 8]) = v;
    }
}

// ---------------------------------------------------------------------------
// main fused kernel: 32 rows/block, 512 threads, 64 KB LDS -> 2 blocks/CU
// ---------------------------------------------------------------------------
__global__ __launch_bounds__(512, 4)
void stk_main(const float* __restrict__ h,
              const int*   __restrict__ topk_idx,
              const float* __restrict__ topk_scores,
              const float* __restrict__ vb, const float* __restrict__ ob,
              const float* __restrict__ gb,
              const unsigned short* __restrict__ wsb,
              float* __restrict__ out)
{
    __shared__ __align__(16) char smem[65536];
    float (*s_P)[512] = reinterpret_cast<float(*)[512]>(smem);

    const int t   = threadIdx.x;
    // XCD swizzle: 256 blocks -> 32 consecutive tiles (2 batches) per XCD
    const int bid = (int)blockIdx.x;
    const int swz = ((bid & 7) << 5) + (bid >> 3);
    const int m0  = swz * ROWS;
    const int batch = m0 >> 9;

    // ---- stage this block's 32 h rows to regs (bf16), consumed later -------
    const int hr = t >> 4;            // 0..31
    const int hc = (t & 15) * 16;     // 16 cols per thread
    short4v hreg[4];
    {
        const float* hrow = h + (size_t)(m0 + hr) * ND + hc;
        #pragma unroll
        for (int u = 0; u < 4; ++u)
            hreg[u] = f2bf4(*reinterpret_cast<const float4*>(hrow + 4 * u));
    }

    // ---- zero P f32 [32][512] (4096 float4 = 512 thr x 8) ------------------
    {
        float4* p4 = reinterpret_cast<float4*>(smem);
        #pragma unroll
        for (int i = 0; i < 8; ++i)
            p4[t + 512 * i] = float4{0.f, 0.f, 0.f, 0.f};
    }

    // ---- softmax over K, two rows per thread -------------------------------
    const int k  = t & 31;
    const int r0 = t >> 5;            // 0..15
    float att[2]; int id[2];
    #pragma unroll
    for (int half = 0; half < 2; ++half) {
        const int r = r0 + (half << 4);
        const size_t off = (size_t)(m0 + r) * NK + k;
        const float s = topk_scores[off];
        id[half] = topk_idx[off];
        float m = s;
        #pragma unroll
        for (int msk = 16; msk >= 1; msk >>= 1)
            m = fmaxf(m, __shfl_xor(m, msk));
        const float p = __expf(s - m);
        float Z = p;
        #pragma unroll
        for (int msk = 16; msk >= 1; msk >>= 1)
            Z += __shfl_xor(Z, msk);
        att[half] = p / Z;
    }
    __syncthreads();                  // P zeroed

    atomicAdd(&s_P[r0][id[0]],      att[0]);
    atomicAdd(&s_P[r0 + 16][id[1]], att[1]);
    __syncthreads();                  // P complete

    // ---- in-register f32->bf16 conversion of P; repartition LDS ------------
    {
        const int pr  = t >> 4;       // row 0..31 (16 thr/row)
        const int pc4 = (t & 15) * 4; // base col
        float4 pch[8];
        #pragma unroll
        for (int u = 0; u < 8; ++u)
            pch[u] = *reinterpret_cast<const float4*>(&s_P[pr][pc4 + 64 * u]);
        __syncthreads();              // all P f32 reads done

        const int xr = (pr & 7) << 4;
        #pragma unroll
        for (int u = 0; u < 8; ++u)
            *reinterpret_cast<short4v*>(
                smem + pr * 1024 + (((pc4 + 64 * u) * 2) ^ xr)) = f2bf4(pch[u]);
        const int xh = (hr & 7) << 4;
        #pragma unroll
        for (int u = 0; u < 4; ++u)
            *reinterpret_cast<short4v*>(
                smem + OFF_HB + hr * 512 + (((hc + 4 * u) * 2) ^ xh)) = hreg[u];
    }
    __syncthreads();                  // Pb + s_hb ready

    const int lane = t & 63, w = t >> 6;
    const int n0 = 2 * w, lr = lane & 15, lg = lane >> 4;
    const int xa = (lr & 7) << 4;     // row-XOR for rows lr and lr+16 (same &7)

    // ---- GEMM1: wsum = Pb @ h_slab ------------------------------------------
    {
        f32x4 acc[2][2] = {{f32x4{0,0,0,0}, f32x4{0,0,0,0}},
                           {f32x4{0,0,0,0}, f32x4{0,0,0,0}}};
        const unsigned short* hf = wsb + (size_t)PHB + (size_t)batch * 131072;
        #pragma unroll
        for (int ks = 0; ks < 16; ++ks) {
            const int cb = (ks * 32 + lg * 8) * 2;
            short8 a[2];
            a[0] = *reinterpret_cast<const short8*>(smem + lr * 1024 + (cb ^ xa));
            a[1] = *reinterpret_cast<const short8*>(smem + (16 + lr) * 1024 + (cb ^ xa));
            #pragma unroll
            for (int n = 0; n < 2; ++n) {
                const short8 b = *reinterpret_cast<const short8*>(
                    &hf[((size_t)(ks * 16 + n0 + n) * 64 + lane) * 8]);
                acc[0][n] = __builtin_amdgcn_mfma_f32_16x16x32_bf16(a[0], b, acc[0][n], 0, 0, 0);
                acc[1][n] = __builtin_amdgcn_mfma_f32_16x16x32_bf16(a[1], b, acc[1][n], 0, 0, 0);
            }
        }
        #pragma unroll
        for (int m = 0; m < 2; ++m)
            #pragma unroll
            for (int n = 0; n < 2; ++n) {
                const int col = (n0 + n) * 16 + lr;
                #pragma unroll
                for (int q = 0; q < 4; ++q) {
                    const int row = m * 16 + 4 * lg + q;
                    *reinterpret_cast<unsigned short*>(
                        smem + OFF_SW + row * 512 + ((col * 2) ^ ((row & 7) << 4))) =
                        f2bf(acc[m][n][q]);
                }
            }
    }
    __syncthreads();                  // s_w ready

    // ---- GEMM2: agg = wsum @ vW + vb ---------------------------------------
    {
        f32x4 acc[2][2];
        #pragma unroll
        for (int n = 0; n < 2; ++n) {
            const float bv = vb[(n0 + n) * 16 + lr];
            acc[0][n] = f32x4{bv, bv, bv, bv};
            acc[1][n] = f32x4{bv, bv, bv, bv};
        }
        #pragma unroll
        for (int ks = 0; ks < 8; ++ks) {
            const int cb = (ks * 32 + lg * 8) * 2;
            short8 a[2];
            a[0] = *reinterpret_cast<const short8*>(smem + OFF_SW + lr * 512 + (cb ^ xa));
            a[1] = *reinterpret_cast<const short8*>(smem + OFF_SW + (16 + lr) * 512 + (cb ^ xa));
            #pragma unroll
            for (int n = 0; n < 2; ++n) {
                const short8 b = *reinterpret_cast<const short8*>(
                    &wsb[(size_t)(PVW + (((n0 + n) * 8 + ks) * 64 + lane) * 8)]);
                acc[0][n] = __builtin_amdgcn_mfma_f32_16x16x32_bf16(a[0], b, acc[0][n], 0, 0, 0);
                acc[1][n] = __builtin_amdgcn_mfma_f32_16x16x32_bf16(a[1], b, acc[1][n], 0, 0, 0);
            }
        }
        // s_ab over dead Pb (region [0,16384)); no reader until next barrier
        #pragma unroll
        for (int m = 0; m < 2; ++m)
            #pragma unroll
            for (int n = 0; n < 2; ++n) {
                const int col = (n0 + n) * 16 + lr;
                #pragma unroll
                for (int q = 0; q < 4; ++q) {
                    const int row = m * 16 + 4 * lg + q;
                    *reinterpret_cast<unsigned short*>(
                        smem + row * 512 + ((col * 2) ^ ((row & 7) << 4))) =
                        f2bf(acc[m][n][q]);
                }
            }
    }
    __syncthreads();                  // s_ab ready

    // ---- GEMM3: o = agg@oW + ob ; g = h@gW_h + agg@gW_a + gb ; epilogue ----
    {
        f32x4 ao[2][2], ag[2][2];
        #pragma unroll
        for (int n = 0; n < 2; ++n) {
            const float bo = ob[(n0 + n) * 16 + lr];
            const float bg = gb[(n0 + n) * 16 + lr];
            ao[0][n] = f32x4{bo, bo, bo, bo}; ao[1][n] = ao[0][n];
            ag[0][n] = f32x4{bg, bg, bg, bg}; ag[1][n] = ag[0][n];
        }
        #pragma unroll
        for (int ks = 0; ks < 8; ++ks) {
            const int cb = (ks * 32 + lg * 8) * 2;
            short8 aa[2], ah[2];
            aa[0] = *reinterpret_cast<const short8*>(smem + lr * 512 + (cb ^ xa));
            aa[1] = *reinterpret_cast<const short8*>(smem + (16 + lr) * 512 + (cb ^ xa));
            ah[0] = *reinterpret_cast<const short8*>(smem + OFF_HB + lr * 512 + (cb ^ xa));
            ah[1] = *reinterpret_cast<const short8*>(smem + OFF_HB + (16 + lr) * 512 + (cb ^ xa));
            #pragma unroll
            for (int n = 0; n < 2; ++n) {
                const int nt = n0 + n;
                const short8 b_o  = *reinterpret_cast<const short8*>(
                    &wsb[(size_t)(POW + ((nt * 8 + ks) * 64 + lane) * 8)]);
                const short8 b_g1 = *reinterpret_cast<const short8*>(
                    &wsb[(size_t)(PGW + ((nt * 16 + ks) * 64 + lane) * 8)]);
                const short8 b_g2 = *reinterpret_cast<const short8*>(
                    &wsb[(size_t)(PGW + ((nt * 16 + ks + 8) * 64 + lane) * 8)]);
                #pragma unroll
                for (int m = 0; m < 2; ++m) {
                    ao[m][n] = __builtin_amdgcn_mfma_f32_16x16x32_bf16(aa[m], b_o,  ao[m][n], 0, 0, 0);
                    ag[m][n] = __builtin_amdgcn_mfma_f32_16x16x32_bf16(ah[m], b_g1, ag[m][n], 0, 0, 0);
                    ag[m][n] = __builtin_amdgcn_mfma_f32_16x16x32_bf16(aa[m], b_g2, ag[m][n], 0, 0, 0);
                }
            }
        }
        #pragma unroll
        for (int m = 0; m < 2; ++m)
            #pragma unroll
            for (int n = 0; n < 2; ++n) {
                const int col = (n0 + n) * 16 + lr;
                #pragma unroll
                for (int q = 0; q < 4; ++q) {
                    const int row = m0 + m * 16 + 4 * lg + q;
                    const float g = 1.f / (1.f + __expf(-ag[m][n][q]));
                    out[(size_t)row * ND + col] = g * ao[m][n][q];
                }
            }
    }
}

// ---------------------------------------------------------------------------
// fallback: proven f32 kernel (used only if ws_size < WS_NEED)
// ---------------------------------------------------------------------------
__global__ __launch_bounds__(512, 2)
void stk_fused(const float* __restrict__ h,
               const int*   __restrict__ topk_idx,
               const float* __restrict__ topk_scores,
               const float* __restrict__ vW, const float* __restrict__ vb,
               const float* __restrict__ oW, const float* __restrict__ ob,
               const float* __restrict__ gW, const float* __restrict__ gb,
               float* __restrict__ out)
{
    __shared__ float s_attn[32][NK];
    __shared__ int   s_idx [32][NK];
    __shared__ float s_wsum[32][ND];
    __shared__ float s_h   [32][ND];
    __shared__ float s_agg [32][ND];

    const int t  = threadIdx.x;
    const int m0 = blockIdx.x * 32;
    const size_t hb = (size_t)(m0 >> 9) * NC * ND;

    {
        const int k  = t & 31;
        const int r0 = t >> 5;
        #pragma unroll
        for (int half = 0; half < 2; ++half) {
            const int r = r0 + (half << 4);
            const size_t off = (size_t)(m0 + r) * NK + k;
            const float s = topk_scores[off];
            const int  id = topk_idx[off];
            float m = s;
            #pragma unroll
            for (int msk = 16; msk >= 1; msk >>= 1) m = fmaxf(m, __shfl_xor(m, msk));
            const float p = __expf(s - m);
            float Z = p;
            #pragma unroll
            for (int msk = 16; msk >= 1; msk >>= 1) Z += __shfl_xor(Z, msk);
            s_attn[r][k] = p / Z;
            s_idx [r][k] = id;
        }
    }
    __syncthreads();

    const int d  = t & 127;
    const int rb = (t >> 7) * 8;

    #pragma unroll
    for (int i = 0; i < 8; ++i) {
        const int r = rb + i;
        const size_t ro = (size_t)(m0 + r) * ND;
        s_h[r][d]       = h[ro + d];
        s_h[r][d + 128] = h[ro + d + 128];
    }
    #pragma unroll 1
    for (int i = 0; i < 8; ++i) {
        const int r = rb + i;
        float a0 = 0.f, a1 = 0.f;
        #pragma unroll 8
        for (int k = 0; k < NK; ++k) {
            const float w  = s_attn[r][k];
            const size_t nb = hb + (size_t)s_idx[r][k] * ND;
            a0 = fmaf(w, h[nb + d],       a0);
            a1 = fmaf(w, h[nb + d + 128], a1);
        }
        s_wsum[r][d]       = a0;
        s_wsum[r][d + 128] = a1;
    }
    __syncthreads();

    float agg0[8], agg1[8];
    {
        const float b0 = vb[d], b1 = vb[d + 128];
        #pragma unroll
        for (int i = 0; i < 8; ++i) { agg0[i] = b0; agg1[i] = b1; }
        for (int e0 = 0; e0 < ND; e0 += 4) {
            float w0[4], w1[4];
            #pragma unroll
            for (int j = 0; j < 4; ++j) {
                w0[j] = vW[(size_t)(e0 + j) * ND + d];
                w1[j] = vW[(size_t)(e0 + j) * ND + d + 128];
            }
            #pragma unroll
            for (int i = 0; i < 8; ++i) {
                const float4 a = *reinterpret_cast<const float4*>(&s_wsum[rb + i][e0]);
                agg0[i] = fmaf(a.x, w0[0], agg0[i]); agg1[i] = fmaf(a.x, w1[0], agg1[i]);
                agg0[i] = fmaf(a.y, w0[1], agg0[i]); agg1[i] = fmaf(a.y, w1[1], agg1[i]);
                agg0[i] = fmaf(a.z, w0[2], agg0[i]); agg1[i] = fmaf(a.z, w1[2], agg1[i]);
                agg0[i] = fmaf(a.w, w0[3], agg0[i]); agg1[i] = fmaf(a.w, w1[3], agg1[i]);
            }
        }
        #pragma unroll
        for (int i = 0; i < 8; ++i) {
            s_agg[rb + i][d]       = agg0[i];
            s_agg[rb + i][d + 128] = agg1[i];
        }
    }
    __syncthreads();

    float o0[8], o1[8], g0[8], g1[8];
    {
        const float obb0 = ob[d], obb1 = ob[d + 128];
        const float gbb0 = gb[d], gbb1 = gb[d + 128];
        #pragma unroll
        for (int i = 0; i < 8; ++i) { o0[i]=obb0; o1[i]=obb1; g0[i]=gbb0; g1[i]=gbb1; }
        for (int e0 = 0; e0 < ND; e0 += 4) {
            float ow0[4], ow1[4], gh0[4], gh1[4], ga0[4], ga1[4];
            #pragma unroll
            for (int j = 0; j < 4; ++j) {
                const size_t er = (size_t)(e0 + j) * ND;
                ow0[j] = oW[er + d];                    ow1[j] = oW[er + d + 128];
                gh0[j] = gW[er + d];                    gh1[j] = gW[er + d + 128];
                ga0[j] = gW[er + (size_t)ND * ND + d];  ga1[j] = gW[er + (size_t)ND * ND + d + 128];
            }
            #pragma unroll
            for (int i = 0; i < 8; ++i) {
                const float4 a  = *reinterpret_cast<const float4*>(&s_agg[rb + i][e0]);
                const float4 hh = *reinterpret_cast<const float4*>(&s_h  [rb + i][e0]);
                o0[i] = fmaf(a.x, ow0[0], o0[i]); o0[i] = fmaf(a.y, ow0[1], o0[i]);
                o0[i] = fmaf(a.z, ow0[2], o0[i]); o0[i] = fmaf(a.w, ow0[3], o0[i]);
                o1[i] = fmaf(a.x, ow1[0], o1[i]); o1[i] = fmaf(a.y, ow1[1], o1[i]);
                o1[i] = fmaf(a.z, ow1[2], o1[i]); o1[i] = fmaf(a.w, ow1[3], o1[i]);
                g0[i] = fmaf(hh.x, gh0[0], g0[i]); g0[i] = fmaf(hh.y, gh0[1], g0[i]);
                g0[i] = fmaf(hh.z, gh0[2], g0[i]); g0[i] = fmaf(hh.w, gh0[3], g0[i]);
                g1[i] = fmaf(hh.x, gh1[0], g1[i]); g1[i] = fmaf(hh.y, gh1[1], g1[i]);
                g1[i] = fmaf(hh.z, gh1[2], g1[i]); g1[i] = fmaf(hh.w, gh1[3], g1[i]);
                g0[i] = fmaf(a.x, ga0[0], g0[i]); g0[i] = fmaf(a.y, ga0[1], g0[i]);
                g0[i] = fmaf(a.z, ga0[2], g0[i]); g0[i] = fmaf(a.w, ga0[3], g0[i]);
                g1[i] = fmaf(a.x, ga1[0], g1[i]); g1[i] = fmaf(a.y, ga1[1], g1[i]);
                g1[i] = fmaf(a.z, ga1[2], g1[i]); g1[i] = fmaf(a.w, ga1[3], g1[i]);
            }
        }
    }
    #pragma unroll
    for (int i = 0; i < 8; ++i) {
        const size_t ro = (size_t)(m0 + rb + i) * ND;
        const float sg0 = 1.f / (1.f + __expf(-g0[i]));
        const float sg1 = 1.f / (1.f + __expf(-g1[i]));
        out[ro + d]       = sg0 * o0[i];
        out[ro + d + 128] = sg1 * o1[i];
    }
}

extern "C" void kernel_launch(void* const* d_in, const int* in_sizes, int n_in,
                              void* d_out, int out_size, void* d_ws, size_t ws_size,
                              hipStream_t stream) {
    const float* h   = (const float*)d_in[0];
    const int*   idx = (const int*)  d_in[1];
    const float* sc  = (const float*)d_in[2];
    const float* vW  = (const float*)d_in[3];
    const float* vb  = (const float*)d_in[4];
    const float* oW  = (const float*)d_in[5];
    const float* ob  = (const float*)d_in[6];
    const float* gW  = (const float*)d_in[7];
    const float* gb  = (const float*)d_in[8];
    float* out = (float*)d_out;

    if (ws_size >= WS_NEED) {
        unsigned short* wsb = (unsigned short*)d_ws;
        stk_pack_all<<<1152, 256, 0, stream>>>(vW, oW, gW, h, wsb);
        stk_main    <<<NBLK, NTHR, 0, stream>>>(h, idx, sc, vb, ob, gb, wsb, out);
    } else {
        stk_fused<<<256, 512, 0, stream>>>(h, idx, sc, vW, vb, oW, ob, gW, gb, out);
    }
}